// Round 16
// baseline (125.528 us; speedup 1.0000x reference)
//
#include <hip/hip_runtime.h>

// MAB block: q=QWq^T+bq, k=(VWk^T+bk)*scale, v=VWv^T+bv, 8-head masked
// attention with residual (Oh = qh + A@vh), merge heads,
// out = O + relu(O Wo^T + bo).  B=4, N=2048, DIM=512, HEADS=8, d=64.
// All compute bf16-MFMA with f32 accumulation.

typedef __attribute__((ext_vector_type(8))) __bf16 bf16x8;
typedef __attribute__((ext_vector_type(4))) float f32x4;

#define DEV static __device__ __forceinline__

constexpr int DIMC = 512;
constexpr int NTOK = 2048;
constexpr int BB   = 4;
constexpr int MTOK = BB * NTOK;          // 8192
constexpr float SCALE2 = 0.04419417382415922f * 1.4426950408889634f; // /sqrt(512)*log2(e)

DEV unsigned short f2b(float f) {        // f32 -> bf16 bits, RNE (finite inputs)
  unsigned u = __float_as_uint(f);
  u = (u + 0x7FFFu + ((u >> 16) & 1u)) >> 16;
  return (unsigned short)u;
}
DEV float b2f(unsigned short b) { return __uint_as_float(((unsigned)b) << 16); }

DEV unsigned cvtpk(float a, float b) {   // {lo=bf16(a), hi=bf16(b)}
  unsigned r;
  asm("v_cvt_pk_bf16_f32 %0, %1, %2" : "=v"(r) : "v"(a), "v"(b));
  return r;
}

DEV bf16x8 pack8(unsigned d0, unsigned d1, unsigned d2, unsigned d3) {
  union { unsigned u[4]; bf16x8 v; } t;
  t.u[0] = d0; t.u[1] = d1; t.u[2] = d2; t.u[3] = d3;
  return t.v;
}

DEV void async_cp16(const void* src, void* dst) {
  __builtin_amdgcn_global_load_lds(
      (const __attribute__((address_space(1))) void*)(src),
      (__attribute__((address_space(3))) void*)(dst), 16, 0, 0);
}

// ------------- f32 -> bf16 conversion (4 weights) + mask detect -------------
__global__ void cvt_all(const float* __restrict__ Wq, const float* __restrict__ Wk,
                        const float* __restrict__ Wv, const float* __restrict__ Wo,
                        unsigned short* __restrict__ Wqb, unsigned short* __restrict__ Wkb,
                        unsigned short* __restrict__ Wvb, unsigned short* __restrict__ Wob,
                        const unsigned char* __restrict__ mask, int* __restrict__ flag) {
  if (blockIdx.x == 4096) {  // mask dtype detect: bool(1B) vs int/float(4B 0/1)
    int any = 0;
    for (int i = threadIdx.x; i < BB * NTOK; i += blockDim.x)
      if ((i & 3) == 1 && mask[i]) any = 1;
    if (any) atomicOr(flag, 1);
    return;
  }
  int i = blockIdx.x * blockDim.x + threadIdx.x;  // float4 index, 4 x 65536
  int wsel = i >> 16, off = i & 65535;
  const float* s = (wsel == 0) ? Wq : (wsel == 1) ? Wk : (wsel == 2) ? Wv : Wo;
  unsigned short* d = (wsel == 0) ? Wqb : (wsel == 1) ? Wkb : (wsel == 2) ? Wvb : Wob;
  float4 v = reinterpret_cast<const float4*>(s)[off];
  ushort4 o;
  o.x = f2b(v.x); o.y = f2b(v.y); o.z = f2b(v.z); o.w = f2b(v.w);
  reinterpret_cast<ushort4*>(d)[off] = o;
}

// ---------------- fused projection GEMM (LDS-staged, 128x128, BK=32) ----------------
// grid (64 rowt, 4 colt, 2 region): region 0 = q-proj; region 1 = k AND v proj
// FUSED -- the staged V-A f32 tile feeds BOTH Wk and Wv MFMAs (32/step),
// halving A staging for the V side. x-major so colt-siblings share an XCD.
// A staged f32 + in-register cvt_pk; W staged bf16.
__global__ __launch_bounds__(256) void proj_gemm(
    const float* __restrict__ Qf, const float* __restrict__ Vf,
    const unsigned short* __restrict__ Wqb, const unsigned short* __restrict__ Wkb,
    const unsigned short* __restrict__ Wvb,
    const float* __restrict__ bq, const float* __restrict__ bk,
    const float* __restrict__ bv,
    unsigned short* __restrict__ qbf, unsigned short* __restrict__ kbf,
    unsigned short* __restrict__ vtb) {
  __shared__ union {
    struct { float A[2][4096]; unsigned short Bk[2][4096]; unsigned short Bv[2][4096]; } s;  // 64KB
    unsigned short LT[128 * 136];                                // 34816B
  } lds;

  const int region = blockIdx.z;
  const float* Af = (region == 0) ? Qf : Vf;

  const int tid = threadIdx.x;
  const int lane = tid & 63;
  const int w = tid >> 6;
  const int r = lane & 15, g = lane >> 4;
  const int rowB = blockIdx.x * 128;           // block row (token) base
  const int colB = blockIdx.y * 128;           // block col (dv) base
  const int rw = (w >> 1) * 64, cw = (w & 1) * 64;

  auto stageA = [&](float* dst, int kk) {      // 128 rows x 32 f32
#pragma unroll
    for (int i = 0; i < 4; ++i) {
      int off = i * 4096 + tid * 16;
      int row = off >> 7;
      int c = ((off >> 4) & 7) ^ (row & 7);
      async_cp16(Af + (size_t)(rowB + row) * DIMC + kk + c * 4, (char*)dst + off);
    }
  };
  auto stageB = [&](unsigned short* dst, const unsigned short* W, int kk) {
#pragma unroll
    for (int i = 0; i < 2; ++i) {
      int off = i * 4096 + tid * 16;
      int row = off >> 6;
      int c = ((off >> 4) & 3) ^ (row & 3);
      async_cp16(W + (size_t)(colB + row) * DIMC + kk + c * 8, (char*)dst + off);
    }
  };

  f32x4 acck[4][4], accv[4][4];
#pragma unroll
  for (int i = 0; i < 4; ++i)
#pragma unroll
    for (int j = 0; j < 4; ++j) {
      acck[i][j] = f32x4{0.f, 0.f, 0.f, 0.f};
      accv[i][j] = f32x4{0.f, 0.f, 0.f, 0.f};
    }

  stageA(lds.s.A[0], 0);
  stageB(lds.s.Bk[0], (region == 0) ? Wqb : Wkb, 0);
  if (region == 1) stageB(lds.s.Bv[0], Wvb, 0);
  __syncthreads();

  int cur = 0;
  for (int kk = 0; kk < DIMC; kk += 32) {
    if (kk + 32 < DIMC) {
      stageA(lds.s.A[cur ^ 1], kk + 32);
      stageB(lds.s.Bk[cur ^ 1], (region == 0) ? Wqb : Wkb, kk + 32);
      if (region == 1) stageB(lds.s.Bv[cur ^ 1], Wvb, kk + 32);
    }
    const char* ap = (const char*)lds.s.A[cur];
    const char* bpk = (const char*)lds.s.Bk[cur];
    const char* bpv = (const char*)lds.s.Bv[cur];
    bf16x8 af[4], bwk[4];
#pragma unroll
    for (int i = 0; i < 4; ++i) {
      int row = rw + i * 16 + r;
      f32x4 lo = *reinterpret_cast<const f32x4*>(
          ap + row * 128 + (((2 * g) ^ (row & 7)) << 4));
      f32x4 hi = *reinterpret_cast<const f32x4*>(
          ap + row * 128 + (((2 * g + 1) ^ (row & 7)) << 4));
      af[i] = pack8(cvtpk(lo[0], lo[1]), cvtpk(lo[2], lo[3]),
                    cvtpk(hi[0], hi[1]), cvtpk(hi[2], hi[3]));
    }
#pragma unroll
    for (int j = 0; j < 4; ++j) {
      int row = cw + j * 16 + r;
      bwk[j] = *reinterpret_cast<const bf16x8*>(bpk + row * 64 + ((g ^ (row & 3)) * 16));
    }
    __builtin_amdgcn_s_setprio(1);
#pragma unroll
    for (int i = 0; i < 4; ++i)
#pragma unroll
      for (int j = 0; j < 4; ++j)
        acck[i][j] = __builtin_amdgcn_mfma_f32_16x16x32_bf16(af[i], bwk[j],
                                                             acck[i][j], 0, 0, 0);
    __builtin_amdgcn_s_setprio(0);
    if (region == 1) {
      bf16x8 bwv[4];
#pragma unroll
      for (int j = 0; j < 4; ++j) {
        int row = cw + j * 16 + r;
        bwv[j] = *reinterpret_cast<const bf16x8*>(bpv + row * 64 + ((g ^ (row & 3)) * 16));
      }
      __builtin_amdgcn_s_setprio(1);
#pragma unroll
      for (int i = 0; i < 4; ++i)
#pragma unroll
        for (int j = 0; j < 4; ++j)
          accv[i][j] = __builtin_amdgcn_mfma_f32_16x16x32_bf16(af[i], bwv[j],
                                                               accv[i][j], 0, 0, 0);
      __builtin_amdgcn_s_setprio(0);
    }
    __syncthreads();
    cur ^= 1;
  }

  if (region == 0) {  // q: natural [tok][dv] bf16 store
#pragma unroll
    for (int i = 0; i < 4; ++i)
#pragma unroll
      for (int j = 0; j < 4; ++j) {
        int n = colB + cw + j * 16 + r;
        float bn = bq[n];
#pragma unroll
        for (int q = 0; q < 4; ++q) {
          int m = rowB + rw + i * 16 + g * 4 + q;
          qbf[(size_t)m * DIMC + n] = f2b(acck[i][j][q] + bn);
        }
      }
  } else {
    // k: natural [tok][dv] store, pre-scaled by SCALE2
#pragma unroll
    for (int i = 0; i < 4; ++i)
#pragma unroll
      for (int j = 0; j < 4; ++j) {
        int n = colB + cw + j * 16 + r;
        float bn = bk[n];
#pragma unroll
        for (int q = 0; q < 4; ++q) {
          int m = rowB + rw + i * 16 + g * 4 + q;
          kbf[(size_t)m * DIMC + n] = f2b((acck[i][j][q] + bn) * SCALE2);
        }
      }
    // v: transpose 128x128 through LDS, store dense [d][tok] rows
#pragma unroll
    for (int i = 0; i < 4; ++i)
#pragma unroll
      for (int j = 0; j < 4; ++j) {
        int nl = cw + j * 16 + r;             // local dv 0..127
        float bn = bv[colB + nl];
        int tl = rw + i * 16 + g * 4;         // local token base (mult of 4)
        ushort4 o;
        o.x = f2b(accv[i][j][0] + bn);
        o.y = f2b(accv[i][j][1] + bn);
        o.z = f2b(accv[i][j][2] + bn);
        o.w = f2b(accv[i][j][3] + bn);
        *reinterpret_cast<ushort4*>(&lds.LT[nl * 136 + tl]) = o;
      }
    __syncthreads();
    int bidx = rowB >> 11, t0 = rowB & 2047;
#pragma unroll
    for (int rd = 0; rd < 8; ++rd) {
      int idx = rd * 256 + tid;               // 128 dv x 16 chunks
      int dv = idx >> 4, ch = idx & 15;
      int gdv = colB + dv, h = gdv >> 6, dd = gdv & 63;
      ushort4 v0 = *reinterpret_cast<const ushort4*>(&lds.LT[dv * 136 + ch * 8]);
      ushort4 v1 = *reinterpret_cast<const ushort4*>(&lds.LT[dv * 136 + ch * 8 + 4]);
      unsigned short* dst = vtb + (size_t)((bidx * 8 + h) * 64 + dd) * NTOK + t0 + ch * 8;
      reinterpret_cast<ushort4*>(dst)[0] = v0;
      reinterpret_cast<ushort4*>(dst)[1] = v1;
    }
  }
}

// ---------------- output GEMM: out = bf16O + relu(bf16O Wo^T + bo) ----------------
// grid (64 rowt, 4 colt): 128x128 block tile (proj region0 skeleton, bf16 A).
// 4 waves (2x2), wave tile 64x64 (4x4 frags); A+B staged bf16, 32KB LDS ->
// 4 blocks/CU. Doubles MFMAs per staged byte vs the old 64x128 tile.
__global__ __launch_bounds__(256) void out_gemm(
    const unsigned short* __restrict__ Obf, const unsigned short* __restrict__ W,
    const float* __restrict__ bias, float* __restrict__ outf) {
  __shared__ struct { unsigned short A[2][4096]; unsigned short B[2][4096]; } lds;  // 32KB

  const int tid = threadIdx.x;
  const int lane = tid & 63;
  const int w = tid >> 6;
  const int r = lane & 15, g = lane >> 4;
  const int rowB = blockIdx.x * 128;
  const int colB = blockIdx.y * 128;
  const int rw = (w >> 1) * 64, cw = (w & 1) * 64;

  auto stage = [&](unsigned short* dst, const unsigned short* src, int kk) {
#pragma unroll
    for (int i = 0; i < 2; ++i) {           // 128 rows x 32 bf16 = 8KB
      int off = i * 4096 + tid * 16;
      int row = off >> 6;
      int c = ((off >> 4) & 3) ^ (row & 3);
      async_cp16(src + (size_t)row * DIMC + kk + c * 8, (char*)dst + off);
    }
  };

  f32x4 acc[4][4];
#pragma unroll
  for (int i = 0; i < 4; ++i)
#pragma unroll
    for (int j = 0; j < 4; ++j) acc[i][j] = f32x4{0.f, 0.f, 0.f, 0.f};

  const unsigned short* Arow = Obf + (size_t)rowB * DIMC;
  const unsigned short* Brow = W + (size_t)colB * DIMC;
  stage(lds.A[0], Arow, 0);
  stage(lds.B[0], Brow, 0);
  __syncthreads();

  int cur = 0;
  for (int kk = 0; kk < DIMC; kk += 32) {
    if (kk + 32 < DIMC) {
      stage(lds.A[cur ^ 1], Arow, kk + 32);
      stage(lds.B[cur ^ 1], Brow, kk + 32);
    }
    const char* ap = (const char*)lds.A[cur];
    const char* bp = (const char*)lds.B[cur];
    bf16x8 af[4], bw[4];
#pragma unroll
    for (int i = 0; i < 4; ++i) {
      int row = rw + i * 16 + r;
      af[i] = *reinterpret_cast<const bf16x8*>(ap + row * 64 + ((g ^ (row & 3)) * 16));
    }
#pragma unroll
    for (int j = 0; j < 4; ++j) {
      int row = cw + j * 16 + r;
      bw[j] = *reinterpret_cast<const bf16x8*>(bp + row * 64 + ((g ^ (row & 3)) * 16));
    }
    __builtin_amdgcn_s_setprio(1);
#pragma unroll
    for (int i = 0; i < 4; ++i)
#pragma unroll
      for (int j = 0; j < 4; ++j)
        acc[i][j] = __builtin_amdgcn_mfma_f32_16x16x32_bf16(af[i], bw[j],
                                                            acc[i][j], 0, 0, 0);
    __builtin_amdgcn_s_setprio(0);
    __syncthreads();
    cur ^= 1;
  }

#pragma unroll
  for (int i = 0; i < 4; ++i)
#pragma unroll
    for (int j = 0; j < 4; ++j) {
      int n = colB + cw + j * 16 + r;
      float bn = bias[n];
#pragma unroll
      for (int q = 0; q < 4; ++q) {
        int m = rowB + rw + i * 16 + g * 4 + q;
        float val = acc[i][j][q] + bn;
        outf[(size_t)m * DIMC + n] =
            b2f(Obf[(size_t)m * DIMC + n]) + fmaxf(val, 0.f);
      }
    }
}

// ---------------- fused masked attention, in-block split-K ----------------
// (round-12 best config.) grid (32 bh, 16 qt), 512 threads = 8 waves. Wave =
// (kg, wq): kg picks even/odd 64-key tiles, wq the 32-q sub-block; each q-row
// covered by a PAIR of waves splitting the key axis -> 4096 waves = 4/SIMD
// with 32q/wave LDS economics. Fixed-max softmax => pair partials combine by
// pure ADDITION through reused LDS. Mask folded into QK MFMA C-init; K rows
// sigma-PERMUTED so swapped-QK^T D-layout per lane IS the PV A-frag order.
// Writes O in bf16 (residual included).
__global__ __launch_bounds__(512, 4) void attn_kernel(
    const unsigned short* __restrict__ qb, const unsigned short* __restrict__ kb,
    const unsigned short* __restrict__ vt, const unsigned char* __restrict__ mask8,
    const int* __restrict__ flagp, unsigned short* __restrict__ Obf) {
  __shared__ unsigned short Kt[2][2][64 * 64];  // [pairbuf][tile]: 8KB each, 32KB
  __shared__ unsigned short Vt[2][2][64 * 64];  // [pairbuf][tile]: 32KB
  __shared__ float MaskAdd[NTOK];               // 8KB: 0 or -16384

  const int tid = threadIdx.x;
  const int lane = tid & 63;
  const int w = tid >> 6;                       // 0..7
  const int kg = w >> 2;                        // key-group: 0=even, 1=odd tile
  const int wq = w & 3;                         // q sub-block
  const int r = lane & 15, g = lane >> 4;
  const int bh = blockIdx.x, b = bh >> 3, h = bh & 7;
  const int q0 = blockIdx.y * 128 + wq * 32;
  const size_t rowbase = (size_t)b * NTOK;
  const int flag = *flagp;
  const unsigned* mask32 = (const unsigned*)mask8;

  for (int i = tid; i < NTOK; i += 512) {
    unsigned v = flag ? (unsigned)mask8[b * NTOK + i] : mask32[b * NTOK + i];
    MaskAdd[i] = v ? 0.f : -16384.f;
  }

  bf16x8 aq0[2], aq1[2];
#pragma unroll
  for (int ks = 0; ks < 2; ++ks) {
    aq0[ks] = *reinterpret_cast<const bf16x8*>(
        qb + (rowbase + q0 + r) * DIMC + h * 64 + ks * 32 + g * 8);
    aq1[ks] = *reinterpret_cast<const bf16x8*>(
        qb + (rowbase + q0 + 16 + r) * DIMC + h * 64 + ks * 32 + g * 8);
  }

  const unsigned short* kgb = kb + rowbase * DIMC + h * 64;  // + key*512
  const unsigned short* vgb = vt + (size_t)bh * 64 * NTOK;   // + d*2048 + key

  auto stageK = [&](int pb, int tile, int kt) {
    int off = tid * 16;                           // byte offset in 8KB tile
    int row = off >> 7;                           // tile row 0..63
    int s16 = ((off >> 4) & 7) ^ (row & 7);       // swizzled 16B slot
    int ff = row >> 4, gg = (row >> 2) & 3, j = row & 3;
    int tok = 8 * gg + 4 * (ff & 1) + 32 * (ff >> 1) + j;   // sigma(row)
    async_cp16(kgb + (size_t)(kt + tok) * DIMC + (s16 << 3),
               (char*)&Kt[pb][tile][0] + off);
  };
  auto stageV = [&](int pb, int tile, int kt) {
    int off = tid * 16;
    int row = off >> 7;                           // d 0..63, keys natural
    int s16 = ((off >> 4) & 7) ^ (row & 7);
    async_cp16(vgb + (size_t)row * NTOK + kt + (s16 << 3),
               (char*)&Vt[pb][tile][0] + off);
  };
  auto stagePair = [&](int pb, int p) {           // 4 cp16 / thread / pair
    stageK(pb, 0, p * 128);
    stageK(pb, 1, p * 128 + 64);
    stageV(pb, 0, p * 128);
    stageV(pb, 1, p * 128 + 64);
  };

  stagePair(0, 0);
  __syncthreads();

  float lrun0 = 0.f, lrun1 = 0.f;
  f32x4 oacc0[4], oacc1[4];
#pragma unroll
  for (int f = 0; f < 4; ++f) {
    oacc0[f] = f32x4{0.f, 0.f, 0.f, 0.f};
    oacc1[f] = f32x4{0.f, 0.f, 0.f, 0.f};
  }

  const int swz = (r & 7) << 4;

  auto softmax_pa = [&](f32x4 (&s)[4], float& lr, bf16x8 (&pa)[2]) {
#pragma unroll
    for (int f = 0; f < 4; ++f)
#pragma unroll
      for (int j = 0; j < 4; ++j) s[f][j] = __builtin_exp2f(s[f][j]);
    float sf[4];
#pragma unroll
    for (int f = 0; f < 4; ++f)
      sf[f] = (s[f][0] + s[f][1]) + (s[f][2] + s[f][3]);
    lr += (sf[0] + sf[1]) + (sf[2] + sf[3]);
#pragma unroll
    for (int ks = 0; ks < 2; ++ks)
      pa[ks] = pack8(cvtpk(s[2 * ks][0], s[2 * ks][1]),
                     cvtpk(s[2 * ks][2], s[2 * ks][3]),
                     cvtpk(s[2 * ks + 1][0], s[2 * ks + 1][1]),
                     cvtpk(s[2 * ks + 1][2], s[2 * ks + 1][3]));
  };

  int cur = 0;
  for (int p = 0; p < NTOK / 128; ++p) {          // 16 pair-iterations
    if (p + 1 < NTOK / 128) stagePair(cur ^ 1, p + 1);

    const int kt = p * 128 + kg * 64;             // this wave's tile

    f32x4 s0[4], s1[4];
#pragma unroll
    for (int f = 0; f < 4; ++f) {
      int tb = kt + 8 * g + 4 * (f & 1) + 32 * (f >> 1);
      f32x4 mc = *reinterpret_cast<const f32x4*>(&MaskAdd[tb]);
      s0[f] = mc;
      s1[f] = mc;
    }
    const unsigned char* kp = (const unsigned char*)&Kt[cur][kg][0];
    __builtin_amdgcn_s_setprio(1);
#pragma unroll
    for (int ks = 0; ks < 2; ++ks)
#pragma unroll
      for (int f = 0; f < 4; ++f) {
        bf16x8 kf = *reinterpret_cast<const bf16x8*>(
            kp + (f * 16 + r) * 128 + ((ks * 64 + g * 16) ^ swz));
        s0[f] = __builtin_amdgcn_mfma_f32_16x16x32_bf16(kf, aq0[ks], s0[f], 0, 0, 0);
        s1[f] = __builtin_amdgcn_mfma_f32_16x16x32_bf16(kf, aq1[ks], s1[f], 0, 0, 0);
      }
    __builtin_amdgcn_s_setprio(0);

    bf16x8 pa0[2], pa1[2];
    softmax_pa(s0, lrun0, pa0);
    softmax_pa(s1, lrun1, pa1);

    const unsigned char* vp = (const unsigned char*)&Vt[cur][kg][0];
    __builtin_amdgcn_s_setprio(1);
#pragma unroll
    for (int ks = 0; ks < 2; ++ks)
#pragma unroll
      for (int f = 0; f < 4; ++f) {
        bf16x8 vf = *reinterpret_cast<const bf16x8*>(
            vp + (f * 16 + r) * 128 + ((ks * 64 + g * 16) ^ swz));
        oacc0[f] = __builtin_amdgcn_mfma_f32_16x16x32_bf16(pa0[ks], vf, oacc0[f], 0, 0, 0);
        oacc1[f] = __builtin_amdgcn_mfma_f32_16x16x32_bf16(pa1[ks], vf, oacc1[f], 0, 0, 0);
      }
    __builtin_amdgcn_s_setprio(0);

    __syncthreads();  // all waves done with pairbuf cur; prefetch landed
    cur ^= 1;
  }

  // row-sum reduce across g-groups (each lane -> its row's partial sum)
  lrun0 += __shfl_xor(lrun0, 16);
  lrun0 += __shfl_xor(lrun0, 32);
  lrun1 += __shfl_xor(lrun1, 16);
  lrun1 += __shfl_xor(lrun1, 32);

  // cross-kg combine through LDS (fixed-max => pure addition). Reuse Kt/Vt.
  f32x4* cb4 = (f32x4*)&Kt[0][0][0];              // 2048 f32x4 = 32KB
  float* cl = (float*)&Vt[0][0][0];               // 128 floats
  if (kg == 1) {
#pragma unroll
    for (int f = 0; f < 4; ++f) {
      cb4[wq * 512 + f * 64 + lane] = oacc0[f];
      cb4[wq * 512 + (4 + f) * 64 + lane] = oacc1[f];
    }
    if (g == 0) {
      cl[wq * 32 + r] = lrun0;
      cl[wq * 32 + 16 + r] = lrun1;
    }
  }
  __syncthreads();
  if (kg == 0) {
#pragma unroll
    for (int f = 0; f < 4; ++f) {
      oacc0[f] += cb4[wq * 512 + f * 64 + lane];
      oacc1[f] += cb4[wq * 512 + (4 + f) * 64 + lane];
    }
    lrun0 += cl[wq * 32 + r];
    lrun1 += cl[wq * 32 + 16 + r];

    auto epilogue = [&](float lr, f32x4 (&oa)[4], int qoff) {
#pragma unroll
      for (int j = 0; j < 4; ++j) {
        float linv = 1.0f / __shfl(lr, (lane & 48) | (g * 4 + j));
        int row = q0 + qoff + g * 4 + j;
#pragma unroll
        for (int f = 0; f < 4; ++f) {
          int col = h * 64 + f * 16 + r;
          size_t idx = (rowbase + row) * DIMC + col;
          Obf[idx] = f2b(b2f(qb[idx]) + oa[f][j] * linv);
        }
      }
    };
    epilogue(lrun0, oacc0, 0);
    epilogue(lrun1, oacc1, 16);
  }
}

extern "C" void kernel_launch(void* const* d_in, const int* in_sizes, int n_in,
                              void* d_out, int out_size, void* d_ws, size_t ws_size,
                              hipStream_t stream) {
  const float* Q  = (const float*)d_in[0];
  const float* V  = (const float*)d_in[1];
  const unsigned char* mask = (const unsigned char*)d_in[2];
  const float* Wq = (const float*)d_in[3];
  const float* bq = (const float*)d_in[4];
  const float* Wk = (const float*)d_in[5];
  const float* bk = (const float*)d_in[6];
  const float* Wv = (const float*)d_in[7];
  const float* bv = (const float*)d_in[8];
  const float* Wo = (const float*)d_in[9];
  const float* bo = (const float*)d_in[10];

  char* ws = (char*)d_ws;
  size_t off = 0;
  auto alloc = [&](size_t bytes) -> void* {
    void* p = ws + off;
    off += (bytes + 255) & ~(size_t)255;
    return p;
  };
  int* flag = (int*)alloc(4);
  unsigned short* Wqb = (unsigned short*)alloc((size_t)DIMC * DIMC * 2);
  unsigned short* Wkb = (unsigned short*)alloc((size_t)DIMC * DIMC * 2);
  unsigned short* Wvb = (unsigned short*)alloc((size_t)DIMC * DIMC * 2);
  unsigned short* Wob = (unsigned short*)alloc((size_t)DIMC * DIMC * 2);
  unsigned short* qbf = (unsigned short*)alloc((size_t)MTOK * DIMC * 2);
  unsigned short* kbf = (unsigned short*)alloc((size_t)MTOK * DIMC * 2);
  unsigned short* vtb = (unsigned short*)alloc((size_t)MTOK * DIMC * 2);
  unsigned short* Obf = (unsigned short*)alloc((size_t)MTOK * DIMC * 2);

  hipMemsetAsync(flag, 0, 4, stream);

  cvt_all<<<4097, 256, 0, stream>>>(Wq, Wk, Wv, Wo, Wqb, Wkb, Wvb, Wob,
                                    mask, flag);

  proj_gemm<<<dim3(64, 4, 2), 256, 0, stream>>>(
      Q, V, Wqb, Wkb, Wvb, bq, bk, bv, qbf, kbf, vtb);

  attn_kernel<<<dim3(BB * 8, NTOK / 128), 512, 0, stream>>>(
      qbf, kbf, vtb, mask, flag, Obf);

  out_gemm<<<dim3(64, 4), 256, 0, stream>>>(
      Obf, Wob, bo, (float*)d_out);
}

// Round 17
// 119.027 us; speedup vs baseline: 1.0546x; 1.0546x over previous
//
#include <hip/hip_runtime.h>

// MAB block: q=QWq^T+bq, k=(VWk^T+bk)*scale, v=VWv^T+bv, 8-head masked
// attention with residual (Oh = qh + A@vh), merge heads,
// out = O + relu(O Wo^T + bo).  B=4, N=2048, DIM=512, HEADS=8, d=64.
// All compute bf16-MFMA with f32 accumulation.
// (Round-15 best configuration, restored after the round-16 out_gemm
// retile regressed: 1 block/CU exposed barrier stalls.)

typedef __attribute__((ext_vector_type(8))) __bf16 bf16x8;
typedef __attribute__((ext_vector_type(4))) float f32x4;

#define DEV static __device__ __forceinline__

constexpr int DIMC = 512;
constexpr int NTOK = 2048;
constexpr int BB   = 4;
constexpr int MTOK = BB * NTOK;          // 8192
constexpr float SCALE2 = 0.04419417382415922f * 1.4426950408889634f; // /sqrt(512)*log2(e)

DEV unsigned short f2b(float f) {        // f32 -> bf16 bits, RNE (finite inputs)
  unsigned u = __float_as_uint(f);
  u = (u + 0x7FFFu + ((u >> 16) & 1u)) >> 16;
  return (unsigned short)u;
}
DEV float b2f(unsigned short b) { return __uint_as_float(((unsigned)b) << 16); }

DEV unsigned cvtpk(float a, float b) {   // {lo=bf16(a), hi=bf16(b)}
  unsigned r;
  asm("v_cvt_pk_bf16_f32 %0, %1, %2" : "=v"(r) : "v"(a), "v"(b));
  return r;
}

DEV bf16x8 pack8(unsigned d0, unsigned d1, unsigned d2, unsigned d3) {
  union { unsigned u[4]; bf16x8 v; } t;
  t.u[0] = d0; t.u[1] = d1; t.u[2] = d2; t.u[3] = d3;
  return t.v;
}

DEV void async_cp16(const void* src, void* dst) {
  __builtin_amdgcn_global_load_lds(
      (const __attribute__((address_space(1))) void*)(src),
      (__attribute__((address_space(3))) void*)(dst), 16, 0, 0);
}

// ------------- f32 -> bf16 conversion (4 weights) + mask detect -------------
__global__ void cvt_all(const float* __restrict__ Wq, const float* __restrict__ Wk,
                        const float* __restrict__ Wv, const float* __restrict__ Wo,
                        unsigned short* __restrict__ Wqb, unsigned short* __restrict__ Wkb,
                        unsigned short* __restrict__ Wvb, unsigned short* __restrict__ Wob,
                        const unsigned char* __restrict__ mask, int* __restrict__ flag) {
  if (blockIdx.x == 4096) {  // mask dtype detect: bool(1B) vs int/float(4B 0/1)
    int any = 0;
    for (int i = threadIdx.x; i < BB * NTOK; i += blockDim.x)
      if ((i & 3) == 1 && mask[i]) any = 1;
    if (any) atomicOr(flag, 1);
    return;
  }
  int i = blockIdx.x * blockDim.x + threadIdx.x;  // float4 index, 4 x 65536
  int wsel = i >> 16, off = i & 65535;
  const float* s = (wsel == 0) ? Wq : (wsel == 1) ? Wk : (wsel == 2) ? Wv : Wo;
  unsigned short* d = (wsel == 0) ? Wqb : (wsel == 1) ? Wkb : (wsel == 2) ? Wvb : Wob;
  float4 v = reinterpret_cast<const float4*>(s)[off];
  ushort4 o;
  o.x = f2b(v.x); o.y = f2b(v.y); o.z = f2b(v.z); o.w = f2b(v.w);
  reinterpret_cast<ushort4*>(d)[off] = o;
}

// ---------------- fused projection GEMM (LDS-staged, 128x128, BK=32) ----------------
// grid (64 rowt, 4 colt, 2 region): region 0 = q-proj; region 1 = k AND v proj
// FUSED -- the staged V-A f32 tile feeds BOTH Wk and Wv MFMAs (32/step),
// halving A staging for the V side. x-major so colt-siblings share an XCD.
// A staged f32 + in-register cvt_pk; W staged bf16.
__global__ __launch_bounds__(256) void proj_gemm(
    const float* __restrict__ Qf, const float* __restrict__ Vf,
    const unsigned short* __restrict__ Wqb, const unsigned short* __restrict__ Wkb,
    const unsigned short* __restrict__ Wvb,
    const float* __restrict__ bq, const float* __restrict__ bk,
    const float* __restrict__ bv,
    unsigned short* __restrict__ qbf, unsigned short* __restrict__ kbf,
    unsigned short* __restrict__ vtb) {
  __shared__ union {
    struct { float A[2][4096]; unsigned short Bk[2][4096]; unsigned short Bv[2][4096]; } s;  // 64KB
    unsigned short LT[128 * 136];                                // 34816B
  } lds;

  const int region = blockIdx.z;
  const float* Af = (region == 0) ? Qf : Vf;

  const int tid = threadIdx.x;
  const int lane = tid & 63;
  const int w = tid >> 6;
  const int r = lane & 15, g = lane >> 4;
  const int rowB = blockIdx.x * 128;           // block row (token) base
  const int colB = blockIdx.y * 128;           // block col (dv) base
  const int rw = (w >> 1) * 64, cw = (w & 1) * 64;

  auto stageA = [&](float* dst, int kk) {      // 128 rows x 32 f32
#pragma unroll
    for (int i = 0; i < 4; ++i) {
      int off = i * 4096 + tid * 16;
      int row = off >> 7;
      int c = ((off >> 4) & 7) ^ (row & 7);
      async_cp16(Af + (size_t)(rowB + row) * DIMC + kk + c * 4, (char*)dst + off);
    }
  };
  auto stageB = [&](unsigned short* dst, const unsigned short* W, int kk) {
#pragma unroll
    for (int i = 0; i < 2; ++i) {
      int off = i * 4096 + tid * 16;
      int row = off >> 6;
      int c = ((off >> 4) & 3) ^ (row & 3);
      async_cp16(W + (size_t)(colB + row) * DIMC + kk + c * 8, (char*)dst + off);
    }
  };

  f32x4 acck[4][4], accv[4][4];
#pragma unroll
  for (int i = 0; i < 4; ++i)
#pragma unroll
    for (int j = 0; j < 4; ++j) {
      acck[i][j] = f32x4{0.f, 0.f, 0.f, 0.f};
      accv[i][j] = f32x4{0.f, 0.f, 0.f, 0.f};
    }

  stageA(lds.s.A[0], 0);
  stageB(lds.s.Bk[0], (region == 0) ? Wqb : Wkb, 0);
  if (region == 1) stageB(lds.s.Bv[0], Wvb, 0);
  __syncthreads();

  int cur = 0;
  for (int kk = 0; kk < DIMC; kk += 32) {
    if (kk + 32 < DIMC) {
      stageA(lds.s.A[cur ^ 1], kk + 32);
      stageB(lds.s.Bk[cur ^ 1], (region == 0) ? Wqb : Wkb, kk + 32);
      if (region == 1) stageB(lds.s.Bv[cur ^ 1], Wvb, kk + 32);
    }
    const char* ap = (const char*)lds.s.A[cur];
    const char* bpk = (const char*)lds.s.Bk[cur];
    const char* bpv = (const char*)lds.s.Bv[cur];
    bf16x8 af[4], bwk[4];
#pragma unroll
    for (int i = 0; i < 4; ++i) {
      int row = rw + i * 16 + r;
      f32x4 lo = *reinterpret_cast<const f32x4*>(
          ap + row * 128 + (((2 * g) ^ (row & 7)) << 4));
      f32x4 hi = *reinterpret_cast<const f32x4*>(
          ap + row * 128 + (((2 * g + 1) ^ (row & 7)) << 4));
      af[i] = pack8(cvtpk(lo[0], lo[1]), cvtpk(lo[2], lo[3]),
                    cvtpk(hi[0], hi[1]), cvtpk(hi[2], hi[3]));
    }
#pragma unroll
    for (int j = 0; j < 4; ++j) {
      int row = cw + j * 16 + r;
      bwk[j] = *reinterpret_cast<const bf16x8*>(bpk + row * 64 + ((g ^ (row & 3)) * 16));
    }
    __builtin_amdgcn_s_setprio(1);
#pragma unroll
    for (int i = 0; i < 4; ++i)
#pragma unroll
      for (int j = 0; j < 4; ++j)
        acck[i][j] = __builtin_amdgcn_mfma_f32_16x16x32_bf16(af[i], bwk[j],
                                                             acck[i][j], 0, 0, 0);
    __builtin_amdgcn_s_setprio(0);
    if (region == 1) {
      bf16x8 bwv[4];
#pragma unroll
      for (int j = 0; j < 4; ++j) {
        int row = cw + j * 16 + r;
        bwv[j] = *reinterpret_cast<const bf16x8*>(bpv + row * 64 + ((g ^ (row & 3)) * 16));
      }
      __builtin_amdgcn_s_setprio(1);
#pragma unroll
      for (int i = 0; i < 4; ++i)
#pragma unroll
        for (int j = 0; j < 4; ++j)
          accv[i][j] = __builtin_amdgcn_mfma_f32_16x16x32_bf16(af[i], bwv[j],
                                                               accv[i][j], 0, 0, 0);
      __builtin_amdgcn_s_setprio(0);
    }
    __syncthreads();
    cur ^= 1;
  }

  if (region == 0) {  // q: natural [tok][dv] bf16 store
#pragma unroll
    for (int i = 0; i < 4; ++i)
#pragma unroll
      for (int j = 0; j < 4; ++j) {
        int n = colB + cw + j * 16 + r;
        float bn = bq[n];
#pragma unroll
        for (int q = 0; q < 4; ++q) {
          int m = rowB + rw + i * 16 + g * 4 + q;
          qbf[(size_t)m * DIMC + n] = f2b(acck[i][j][q] + bn);
        }
      }
  } else {
    // k: natural [tok][dv] store, pre-scaled by SCALE2
#pragma unroll
    for (int i = 0; i < 4; ++i)
#pragma unroll
      for (int j = 0; j < 4; ++j) {
        int n = colB + cw + j * 16 + r;
        float bn = bk[n];
#pragma unroll
        for (int q = 0; q < 4; ++q) {
          int m = rowB + rw + i * 16 + g * 4 + q;
          kbf[(size_t)m * DIMC + n] = f2b((acck[i][j][q] + bn) * SCALE2);
        }
      }
    // v: transpose 128x128 through LDS, store dense [d][tok] rows
#pragma unroll
    for (int i = 0; i < 4; ++i)
#pragma unroll
      for (int j = 0; j < 4; ++j) {
        int nl = cw + j * 16 + r;             // local dv 0..127
        float bn = bv[colB + nl];
        int tl = rw + i * 16 + g * 4;         // local token base (mult of 4)
        ushort4 o;
        o.x = f2b(accv[i][j][0] + bn);
        o.y = f2b(accv[i][j][1] + bn);
        o.z = f2b(accv[i][j][2] + bn);
        o.w = f2b(accv[i][j][3] + bn);
        *reinterpret_cast<ushort4*>(&lds.LT[nl * 136 + tl]) = o;
      }
    __syncthreads();
    int bidx = rowB >> 11, t0 = rowB & 2047;
#pragma unroll
    for (int rd = 0; rd < 8; ++rd) {
      int idx = rd * 256 + tid;               // 128 dv x 16 chunks
      int dv = idx >> 4, ch = idx & 15;
      int gdv = colB + dv, h = gdv >> 6, dd = gdv & 63;
      ushort4 v0 = *reinterpret_cast<const ushort4*>(&lds.LT[dv * 136 + ch * 8]);
      ushort4 v1 = *reinterpret_cast<const ushort4*>(&lds.LT[dv * 136 + ch * 8 + 4]);
      unsigned short* dst = vtb + (size_t)((bidx * 8 + h) * 64 + dd) * NTOK + t0 + ch * 8;
      reinterpret_cast<ushort4*>(dst)[0] = v0;
      reinterpret_cast<ushort4*>(dst)[1] = v1;
    }
  }
}

// ---------------- output GEMM: out = bf16O + relu(bf16O Wo^T + bo) ----------------
// grid (128 rowt, 4 colt) = 512 blocks (2/CU). A staged directly from bf16 O;
// residual read from the same bf16 O (L2-hot).
__global__ __launch_bounds__(256) void out_gemm(
    const unsigned short* __restrict__ Obf, const unsigned short* __restrict__ W,
    const float* __restrict__ bias, float* __restrict__ outf) {
  __shared__ struct { unsigned short A[2][2048]; unsigned short B[2][4096]; } lds;  // 24KB

  const int tid = threadIdx.x;
  const int lane = tid & 63;
  const int w = tid >> 6;
  const int r = lane & 15, g = lane >> 4;
  const int rowB = blockIdx.x * 64;
  const int colB = blockIdx.y * 128;
  const int rw = (w >> 1) * 32, cw = (w & 1) * 64;

  auto stageA = [&](unsigned short* dst, int kk) {  // 64 rows x 32 bf16 (4KB)
    int off = tid * 16;
    int row = off >> 6;
    int c = ((off >> 4) & 3) ^ (row & 3);
    async_cp16(Obf + (size_t)(rowB + row) * DIMC + kk + c * 8, (char*)dst + off);
  };
  auto stageB = [&](unsigned short* dst, int kk) {  // 128 x 32 bf16
#pragma unroll
    for (int i = 0; i < 2; ++i) {
      int off = i * 4096 + tid * 16;
      int row = off >> 6;
      int c = ((off >> 4) & 3) ^ (row & 3);
      async_cp16(W + (size_t)(colB + row) * DIMC + kk + c * 8, (char*)dst + off);
    }
  };

  f32x4 acc[2][4];
#pragma unroll
  for (int i = 0; i < 2; ++i)
#pragma unroll
    for (int j = 0; j < 4; ++j) acc[i][j] = f32x4{0.f, 0.f, 0.f, 0.f};

  stageA(lds.A[0], 0);
  stageB(lds.B[0], 0);
  __syncthreads();

  int cur = 0;
  for (int kk = 0; kk < DIMC; kk += 32) {
    if (kk + 32 < DIMC) {
      stageA(lds.A[cur ^ 1], kk + 32);
      stageB(lds.B[cur ^ 1], kk + 32);
    }
    const char* ap = (const char*)lds.A[cur];
    const char* bp = (const char*)lds.B[cur];
    bf16x8 af[2], bw[4];
#pragma unroll
    for (int i = 0; i < 2; ++i) {
      int row = rw + i * 16 + r;
      af[i] = *reinterpret_cast<const bf16x8*>(ap + row * 64 + ((g ^ (row & 3)) * 16));
    }
#pragma unroll
    for (int j = 0; j < 4; ++j) {
      int row = cw + j * 16 + r;
      bw[j] = *reinterpret_cast<const bf16x8*>(bp + row * 64 + ((g ^ (row & 3)) * 16));
    }
    __builtin_amdgcn_s_setprio(1);
#pragma unroll
    for (int i = 0; i < 2; ++i)
#pragma unroll
      for (int j = 0; j < 4; ++j)
        acc[i][j] = __builtin_amdgcn_mfma_f32_16x16x32_bf16(af[i], bw[j],
                                                            acc[i][j], 0, 0, 0);
    __builtin_amdgcn_s_setprio(0);
    __syncthreads();
    cur ^= 1;
  }

#pragma unroll
  for (int i = 0; i < 2; ++i)
#pragma unroll
    for (int j = 0; j < 4; ++j) {
      int n = colB + cw + j * 16 + r;
      float bn = bias[n];
#pragma unroll
      for (int q = 0; q < 4; ++q) {
        int m = rowB + rw + i * 16 + g * 4 + q;
        float val = acc[i][j][q] + bn;
        outf[(size_t)m * DIMC + n] =
            b2f(Obf[(size_t)m * DIMC + n]) + fmaxf(val, 0.f);
      }
    }
}

// ---------------- fused masked attention, in-block split-K ----------------
// grid (32 bh, 16 qt), 512 threads = 8 waves. Wave = (kg, wq): kg picks
// even/odd 64-key tiles, wq the 32-q sub-block; each q-row covered by a PAIR
// of waves splitting the key axis -> 4096 waves = 4/SIMD with 32q/wave LDS
// economics. Fixed-max softmax => pair partials combine by pure ADDITION
// through reused LDS. Mask folded into QK MFMA C-init; K rows sigma-PERMUTED
// so swapped-QK^T D-layout per lane IS the PV A-frag order. Writes bf16 O.
__global__ __launch_bounds__(512, 4) void attn_kernel(
    const unsigned short* __restrict__ qb, const unsigned short* __restrict__ kb,
    const unsigned short* __restrict__ vt, const unsigned char* __restrict__ mask8,
    const int* __restrict__ flagp, unsigned short* __restrict__ Obf) {
  __shared__ unsigned short Kt[2][2][64 * 64];  // [pairbuf][tile]: 8KB each, 32KB
  __shared__ unsigned short Vt[2][2][64 * 64];  // [pairbuf][tile]: 32KB
  __shared__ float MaskAdd[NTOK];               // 8KB: 0 or -16384

  const int tid = threadIdx.x;
  const int lane = tid & 63;
  const int w = tid >> 6;                       // 0..7
  const int kg = w >> 2;                        // key-group: 0=even, 1=odd tile
  const int wq = w & 3;                         // q sub-block
  const int r = lane & 15, g = lane >> 4;
  const int bh = blockIdx.x, b = bh >> 3, h = bh & 7;
  const int q0 = blockIdx.y * 128 + wq * 32;
  const size_t rowbase = (size_t)b * NTOK;
  const int flag = *flagp;
  const unsigned* mask32 = (const unsigned*)mask8;

  for (int i = tid; i < NTOK; i += 512) {
    unsigned v = flag ? (unsigned)mask8[b * NTOK + i] : mask32[b * NTOK + i];
    MaskAdd[i] = v ? 0.f : -16384.f;
  }

  bf16x8 aq0[2], aq1[2];
#pragma unroll
  for (int ks = 0; ks < 2; ++ks) {
    aq0[ks] = *reinterpret_cast<const bf16x8*>(
        qb + (rowbase + q0 + r) * DIMC + h * 64 + ks * 32 + g * 8);
    aq1[ks] = *reinterpret_cast<const bf16x8*>(
        qb + (rowbase + q0 + 16 + r) * DIMC + h * 64 + ks * 32 + g * 8);
  }

  const unsigned short* kgb = kb + rowbase * DIMC + h * 64;  // + key*512
  const unsigned short* vgb = vt + (size_t)bh * 64 * NTOK;   // + d*2048 + key

  auto stageK = [&](int pb, int tile, int kt) {
    int off = tid * 16;                           // byte offset in 8KB tile
    int row = off >> 7;                           // tile row 0..63
    int s16 = ((off >> 4) & 7) ^ (row & 7);       // swizzled 16B slot
    int ff = row >> 4, gg = (row >> 2) & 3, j = row & 3;
    int tok = 8 * gg + 4 * (ff & 1) + 32 * (ff >> 1) + j;   // sigma(row)
    async_cp16(kgb + (size_t)(kt + tok) * DIMC + (s16 << 3),
               (char*)&Kt[pb][tile][0] + off);
  };
  auto stageV = [&](int pb, int tile, int kt) {
    int off = tid * 16;
    int row = off >> 7;                           // d 0..63, keys natural
    int s16 = ((off >> 4) & 7) ^ (row & 7);
    async_cp16(vgb + (size_t)row * NTOK + kt + (s16 << 3),
               (char*)&Vt[pb][tile][0] + off);
  };
  auto stagePair = [&](int pb, int p) {           // 4 cp16 / thread / pair
    stageK(pb, 0, p * 128);
    stageK(pb, 1, p * 128 + 64);
    stageV(pb, 0, p * 128);
    stageV(pb, 1, p * 128 + 64);
  };

  stagePair(0, 0);
  __syncthreads();

  float lrun0 = 0.f, lrun1 = 0.f;
  f32x4 oacc0[4], oacc1[4];
#pragma unroll
  for (int f = 0; f < 4; ++f) {
    oacc0[f] = f32x4{0.f, 0.f, 0.f, 0.f};
    oacc1[f] = f32x4{0.f, 0.f, 0.f, 0.f};
  }

  const int swz = (r & 7) << 4;

  auto softmax_pa = [&](f32x4 (&s)[4], float& lr, bf16x8 (&pa)[2]) {
#pragma unroll
    for (int f = 0; f < 4; ++f)
#pragma unroll
      for (int j = 0; j < 4; ++j) s[f][j] = __builtin_exp2f(s[f][j]);
    float sf[4];
#pragma unroll
    for (int f = 0; f < 4; ++f)
      sf[f] = (s[f][0] + s[f][1]) + (s[f][2] + s[f][3]);
    lr += (sf[0] + sf[1]) + (sf[2] + sf[3]);
#pragma unroll
    for (int ks = 0; ks < 2; ++ks)
      pa[ks] = pack8(cvtpk(s[2 * ks][0], s[2 * ks][1]),
                     cvtpk(s[2 * ks][2], s[2 * ks][3]),
                     cvtpk(s[2 * ks + 1][0], s[2 * ks + 1][1]),
                     cvtpk(s[2 * ks + 1][2], s[2 * ks + 1][3]));
  };

  int cur = 0;
  for (int p = 0; p < NTOK / 128; ++p) {          // 16 pair-iterations
    if (p + 1 < NTOK / 128) stagePair(cur ^ 1, p + 1);

    const int kt = p * 128 + kg * 64;             // this wave's tile

    f32x4 s0[4], s1[4];
#pragma unroll
    for (int f = 0; f < 4; ++f) {
      int tb = kt + 8 * g + 4 * (f & 1) + 32 * (f >> 1);
      f32x4 mc = *reinterpret_cast<const f32x4*>(&MaskAdd[tb]);
      s0[f] = mc;
      s1[f] = mc;
    }
    const unsigned char* kp = (const unsigned char*)&Kt[cur][kg][0];
    __builtin_amdgcn_s_setprio(1);
#pragma unroll
    for (int ks = 0; ks < 2; ++ks)
#pragma unroll
      for (int f = 0; f < 4; ++f) {
        bf16x8 kf = *reinterpret_cast<const bf16x8*>(
            kp + (f * 16 + r) * 128 + ((ks * 64 + g * 16) ^ swz));
        s0[f] = __builtin_amdgcn_mfma_f32_16x16x32_bf16(kf, aq0[ks], s0[f], 0, 0, 0);
        s1[f] = __builtin_amdgcn_mfma_f32_16x16x32_bf16(kf, aq1[ks], s1[f], 0, 0, 0);
      }
    __builtin_amdgcn_s_setprio(0);

    bf16x8 pa0[2], pa1[2];
    softmax_pa(s0, lrun0, pa0);
    softmax_pa(s1, lrun1, pa1);

    const unsigned char* vp = (const unsigned char*)&Vt[cur][kg][0];
    __builtin_amdgcn_s_setprio(1);
#pragma unroll
    for (int ks = 0; ks < 2; ++ks)
#pragma unroll
      for (int f = 0; f < 4; ++f) {
        bf16x8 vf = *reinterpret_cast<const bf16x8*>(
            vp + (f * 16 + r) * 128 + ((ks * 64 + g * 16) ^ swz));
        oacc0[f] = __builtin_amdgcn_mfma_f32_16x16x32_bf16(pa0[ks], vf, oacc0[f], 0, 0, 0);
        oacc1[f] = __builtin_amdgcn_mfma_f32_16x16x32_bf16(pa1[ks], vf, oacc1[f], 0, 0, 0);
      }
    __builtin_amdgcn_s_setprio(0);

    __syncthreads();  // all waves done with pairbuf cur; prefetch landed
    cur ^= 1;
  }

  // row-sum reduce across g-groups (each lane -> its row's partial sum)
  lrun0 += __shfl_xor(lrun0, 16);
  lrun0 += __shfl_xor(lrun0, 32);
  lrun1 += __shfl_xor(lrun1, 16);
  lrun1 += __shfl_xor(lrun1, 32);

  // cross-kg combine through LDS (fixed-max => pure addition). Reuse Kt/Vt.
  f32x4* cb4 = (f32x4*)&Kt[0][0][0];              // 2048 f32x4 = 32KB
  float* cl = (float*)&Vt[0][0][0];               // 128 floats
  if (kg == 1) {
#pragma unroll
    for (int f = 0; f < 4; ++f) {
      cb4[wq * 512 + f * 64 + lane] = oacc0[f];
      cb4[wq * 512 + (4 + f) * 64 + lane] = oacc1[f];
    }
    if (g == 0) {
      cl[wq * 32 + r] = lrun0;
      cl[wq * 32 + 16 + r] = lrun1;
    }
  }
  __syncthreads();
  if (kg == 0) {
#pragma unroll
    for (int f = 0; f < 4; ++f) {
      oacc0[f] += cb4[wq * 512 + f * 64 + lane];
      oacc1[f] += cb4[wq * 512 + (4 + f) * 64 + lane];
    }
    lrun0 += cl[wq * 32 + r];
    lrun1 += cl[wq * 32 + 16 + r];

    auto epilogue = [&](float lr, f32x4 (&oa)[4], int qoff) {
#pragma unroll
      for (int j = 0; j < 4; ++j) {
        float linv = 1.0f / __shfl(lr, (lane & 48) | (g * 4 + j));
        int row = q0 + qoff + g * 4 + j;
#pragma unroll
        for (int f = 0; f < 4; ++f) {
          int col = h * 64 + f * 16 + r;
          size_t idx = (rowbase + row) * DIMC + col;
          Obf[idx] = f2b(b2f(qb[idx]) + oa[f][j] * linv);
        }
      }
    };
    epilogue(lrun0, oacc0, 0);
    epilogue(lrun1, oacc1, 16);
  }
}

extern "C" void kernel_launch(void* const* d_in, const int* in_sizes, int n_in,
                              void* d_out, int out_size, void* d_ws, size_t ws_size,
                              hipStream_t stream) {
  const float* Q  = (const float*)d_in[0];
  const float* V  = (const float*)d_in[1];
  const unsigned char* mask = (const unsigned char*)d_in[2];
  const float* Wq = (const float*)d_in[3];
  const float* bq = (const float*)d_in[4];
  const float* Wk = (const float*)d_in[5];
  const float* bk = (const float*)d_in[6];
  const float* Wv = (const float*)d_in[7];
  const float* bv = (const float*)d_in[8];
  const float* Wo = (const float*)d_in[9];
  const float* bo = (const float*)d_in[10];

  char* ws = (char*)d_ws;
  size_t off = 0;
  auto alloc = [&](size_t bytes) -> void* {
    void* p = ws + off;
    off += (bytes + 255) & ~(size_t)255;
    return p;
  };
  int* flag = (int*)alloc(4);
  unsigned short* Wqb = (unsigned short*)alloc((size_t)DIMC * DIMC * 2);
  unsigned short* Wkb = (unsigned short*)alloc((size_t)DIMC * DIMC * 2);
  unsigned short* Wvb = (unsigned short*)alloc((size_t)DIMC * DIMC * 2);
  unsigned short* Wob = (unsigned short*)alloc((size_t)DIMC * DIMC * 2);
  unsigned short* qbf = (unsigned short*)alloc((size_t)MTOK * DIMC * 2);
  unsigned short* kbf = (unsigned short*)alloc((size_t)MTOK * DIMC * 2);
  unsigned short* vtb = (unsigned short*)alloc((size_t)MTOK * DIMC * 2);
  unsigned short* Obf = (unsigned short*)alloc((size_t)MTOK * DIMC * 2);

  hipMemsetAsync(flag, 0, 4, stream);

  cvt_all<<<4097, 256, 0, stream>>>(Wq, Wk, Wv, Wo, Wqb, Wkb, Wvb, Wob,
                                    mask, flag);

  proj_gemm<<<dim3(64, 4, 2), 256, 0, stream>>>(
      Q, V, Wqb, Wkb, Wvb, bq, bk, bv, qbf, kbf, vtb);

  attn_kernel<<<dim3(BB * 8, NTOK / 128), 512, 0, stream>>>(
      qbf, kbf, vtb, mask, flag, Obf);

  out_gemm<<<dim3(128, 4), 256, 0, stream>>>(
      Obf, Wob, bo, (float*)d_out);
}

// Round 18
// 112.079 us; speedup vs baseline: 1.1200x; 1.0620x over previous
//
#include <hip/hip_runtime.h>

// MAB block: q=QWq^T+bq, k=(VWk^T+bk)*scale, v=VWv^T+bv, 8-head masked
// attention with residual (Oh = qh + A@vh), merge heads,
// out = O + relu(O Wo^T + bo).  B=4, N=2048, DIM=512, HEADS=8, d=64.
// All compute bf16-MFMA with f32 accumulation.
// This round: cvt_all deleted -- weights staged f32 and converted in-register
// (round-6 path, 8us better than bf16-W + separate conversion pass);
// mask-detect folded into proj block (0,0,0). attn = round-12 best config.

typedef __attribute__((ext_vector_type(8))) __bf16 bf16x8;
typedef __attribute__((ext_vector_type(4))) float f32x4;

#define DEV static __device__ __forceinline__

constexpr int DIMC = 512;
constexpr int NTOK = 2048;
constexpr int BB   = 4;
constexpr int MTOK = BB * NTOK;          // 8192
constexpr float SCALE2 = 0.04419417382415922f * 1.4426950408889634f; // /sqrt(512)*log2(e)

DEV unsigned short f2b(float f) {        // f32 -> bf16 bits, RNE (finite inputs)
  unsigned u = __float_as_uint(f);
  u = (u + 0x7FFFu + ((u >> 16) & 1u)) >> 16;
  return (unsigned short)u;
}
DEV float b2f(unsigned short b) { return __uint_as_float(((unsigned)b) << 16); }

DEV unsigned cvtpk(float a, float b) {   // {lo=bf16(a), hi=bf16(b)}
  unsigned r;
  asm("v_cvt_pk_bf16_f32 %0, %1, %2" : "=v"(r) : "v"(a), "v"(b));
  return r;
}

DEV bf16x8 pack8(unsigned d0, unsigned d1, unsigned d2, unsigned d3) {
  union { unsigned u[4]; bf16x8 v; } t;
  t.u[0] = d0; t.u[1] = d1; t.u[2] = d2; t.u[3] = d3;
  return t.v;
}

DEV void async_cp16(const void* src, void* dst) {
  __builtin_amdgcn_global_load_lds(
      (const __attribute__((address_space(1))) void*)(src),
      (__attribute__((address_space(3))) void*)(dst), 16, 0, 0);
}

// ---------------- fused projection GEMM (LDS-staged, 128x128, BK=32) ----------------
// grid (64 rowt, 4 colt, 3 region): x-major so colt-siblings and regions share
// an XCD -> A panel L2-shared. region 0=q, 1=k(scaled), 2=v(transposed).
// BOTH A and W staged f32, converted in-register (cvt_pk) -- no separate
// weight-conversion kernel. Block (0,0,0) also runs the mask-dtype detect.
__global__ __launch_bounds__(256) void proj_gemm(
    const float* __restrict__ Qf, const float* __restrict__ Vf,
    const float* __restrict__ Wq, const float* __restrict__ Wk,
    const float* __restrict__ Wv,
    const float* __restrict__ bq, const float* __restrict__ bk,
    const float* __restrict__ bv,
    unsigned short* __restrict__ qbf, unsigned short* __restrict__ kbf,
    unsigned short* __restrict__ vtb,
    const unsigned char* __restrict__ mask, int* __restrict__ flag) {
  __shared__ union {
    struct { float A[2][4096]; float B[2][4096]; } s;  // 64KB
    unsigned short LT[128 * 136];                      // 34816B
  } lds;

  const int region = blockIdx.z;
  const float* Af = (region == 0) ? Qf : Vf;
  const float* W = (region == 0) ? Wq : (region == 1) ? Wk : Wv;
  const float* bias = (region == 0) ? bq : (region == 1) ? bk : bv;

  const int tid = threadIdx.x;
  const int lane = tid & 63;
  const int w = tid >> 6;
  const int r = lane & 15, g = lane >> 4;
  const int rowB = blockIdx.x * 128;           // block row (token) base
  const int colB = blockIdx.y * 128;           // block col (dv) base
  const int rw = (w >> 1) * 64, cw = (w & 1) * 64;

  // mask dtype detect: bool(1B) vs int/float(4B 0/1); one block only
  if (region == 0 && blockIdx.x == 0 && blockIdx.y == 0) {
    int any = 0;
    for (int i = tid; i < BB * NTOK; i += 256)
      if ((i & 3) == 1 && mask[i]) any = 1;
    if (any) atomicOr(flag, 1);
  }

  // stage 128 rows x 32 f32 (rows of 128B, slot^=row&7)
  auto stageT = [&](float* dst, const float* src, int kk) {
#pragma unroll
    for (int i = 0; i < 4; ++i) {
      int off = i * 4096 + tid * 16;
      int row = off >> 7;
      int c = ((off >> 4) & 7) ^ (row & 7);
      async_cp16(src + (size_t)row * DIMC + kk + c * 4, (char*)dst + off);
    }
  };

  f32x4 acc[4][4];
#pragma unroll
  for (int i = 0; i < 4; ++i)
#pragma unroll
    for (int j = 0; j < 4; ++j) acc[i][j] = f32x4{0.f, 0.f, 0.f, 0.f};

  stageT(lds.s.A[0], Af + (size_t)rowB * DIMC, 0);
  stageT(lds.s.B[0], W + (size_t)colB * DIMC, 0);
  __syncthreads();

  int cur = 0;
  for (int kk = 0; kk < DIMC; kk += 32) {
    if (kk + 32 < DIMC) {
      stageT(lds.s.A[cur ^ 1], Af + (size_t)rowB * DIMC, kk + 32);
      stageT(lds.s.B[cur ^ 1], W + (size_t)colB * DIMC, kk + 32);
    }
    const char* ap = (const char*)lds.s.A[cur];
    const char* bp = (const char*)lds.s.B[cur];
    bf16x8 af[4], bw[4];
#pragma unroll
    for (int i = 0; i < 4; ++i) {
      int row = rw + i * 16 + r;
      f32x4 lo = *reinterpret_cast<const f32x4*>(
          ap + row * 128 + (((2 * g) ^ (row & 7)) << 4));
      f32x4 hi = *reinterpret_cast<const f32x4*>(
          ap + row * 128 + (((2 * g + 1) ^ (row & 7)) << 4));
      af[i] = pack8(cvtpk(lo[0], lo[1]), cvtpk(lo[2], lo[3]),
                    cvtpk(hi[0], hi[1]), cvtpk(hi[2], hi[3]));
    }
#pragma unroll
    for (int j = 0; j < 4; ++j) {
      int row = cw + j * 16 + r;
      f32x4 lo = *reinterpret_cast<const f32x4*>(
          bp + row * 128 + (((2 * g) ^ (row & 7)) << 4));
      f32x4 hi = *reinterpret_cast<const f32x4*>(
          bp + row * 128 + (((2 * g + 1) ^ (row & 7)) << 4));
      bw[j] = pack8(cvtpk(lo[0], lo[1]), cvtpk(lo[2], lo[3]),
                    cvtpk(hi[0], hi[1]), cvtpk(hi[2], hi[3]));
    }
    __builtin_amdgcn_s_setprio(1);
#pragma unroll
    for (int i = 0; i < 4; ++i)
#pragma unroll
      for (int j = 0; j < 4; ++j)
        acc[i][j] = __builtin_amdgcn_mfma_f32_16x16x32_bf16(af[i], bw[j],
                                                            acc[i][j], 0, 0, 0);
    __builtin_amdgcn_s_setprio(0);
    __syncthreads();
    cur ^= 1;
  }

  if (region != 2) {  // q / k: natural [tok][dv] bf16 store (k pre-scaled)
    const float sc = (region == 1) ? SCALE2 : 1.0f;
    unsigned short* dst = (region == 1) ? kbf : qbf;
#pragma unroll
    for (int i = 0; i < 4; ++i)
#pragma unroll
      for (int j = 0; j < 4; ++j) {
        int n = colB + cw + j * 16 + r;
        float bn = bias[n];
#pragma unroll
        for (int q = 0; q < 4; ++q) {
          int m = rowB + rw + i * 16 + g * 4 + q;
          dst[(size_t)m * DIMC + n] = f2b((acc[i][j][q] + bn) * sc);
        }
      }
  } else {  // v: transpose 128x128 through LDS, store dense [d][tok] rows
#pragma unroll
    for (int i = 0; i < 4; ++i)
#pragma unroll
      for (int j = 0; j < 4; ++j) {
        int nl = cw + j * 16 + r;             // local dv 0..127
        float bn = bias[colB + nl];
        int tl = rw + i * 16 + g * 4;         // local token base (mult of 4)
        ushort4 o;
        o.x = f2b(acc[i][j][0] + bn);
        o.y = f2b(acc[i][j][1] + bn);
        o.z = f2b(acc[i][j][2] + bn);
        o.w = f2b(acc[i][j][3] + bn);
        *reinterpret_cast<ushort4*>(&lds.LT[nl * 136 + tl]) = o;
      }
    __syncthreads();
    int bidx = rowB >> 11, t0 = rowB & 2047;
#pragma unroll
    for (int rd = 0; rd < 8; ++rd) {
      int idx = rd * 256 + tid;               // 128 dv x 16 chunks
      int dv = idx >> 4, ch = idx & 15;
      int gdv = colB + dv, h = gdv >> 6, dd = gdv & 63;
      ushort4 v0 = *reinterpret_cast<const ushort4*>(&lds.LT[dv * 136 + ch * 8]);
      ushort4 v1 = *reinterpret_cast<const ushort4*>(&lds.LT[dv * 136 + ch * 8 + 4]);
      unsigned short* dst = vtb + (size_t)((bidx * 8 + h) * 64 + dd) * NTOK + t0 + ch * 8;
      reinterpret_cast<ushort4*>(dst)[0] = v0;
      reinterpret_cast<ushort4*>(dst)[1] = v1;
    }
  }
}

// ---------------- output GEMM: out = bf16O + relu(bf16O Wo^T + bo) ----------------
// grid (128 rowt, 4 colt) = 512 blocks. A staged bf16 from Obf; Wo staged f32
// and converted in-register. 40KB LDS -> 4 blocks/CU capacity.
__global__ __launch_bounds__(256) void out_gemm(
    const unsigned short* __restrict__ Obf, const float* __restrict__ W,
    const float* __restrict__ bias, float* __restrict__ outf) {
  __shared__ struct { unsigned short A[2][2048]; float B[2][4096]; } lds;  // 40KB

  const int tid = threadIdx.x;
  const int lane = tid & 63;
  const int w = tid >> 6;
  const int r = lane & 15, g = lane >> 4;
  const int rowB = blockIdx.x * 64;
  const int colB = blockIdx.y * 128;
  const int rw = (w >> 1) * 32, cw = (w & 1) * 64;

  auto stageA = [&](unsigned short* dst, int kk) {  // 64 rows x 32 bf16 (4KB)
    int off = tid * 16;
    int row = off >> 6;
    int c = ((off >> 4) & 3) ^ (row & 3);
    async_cp16(Obf + (size_t)(rowB + row) * DIMC + kk + c * 8, (char*)dst + off);
  };
  auto stageB = [&](float* dst, int kk) {  // 128 rows x 32 f32 (16KB)
#pragma unroll
    for (int i = 0; i < 4; ++i) {
      int off = i * 4096 + tid * 16;
      int row = off >> 7;
      int c = ((off >> 4) & 7) ^ (row & 7);
      async_cp16(W + (size_t)(colB + row) * DIMC + kk + c * 4, (char*)dst + off);
    }
  };

  f32x4 acc[2][4];
#pragma unroll
  for (int i = 0; i < 2; ++i)
#pragma unroll
    for (int j = 0; j < 4; ++j) acc[i][j] = f32x4{0.f, 0.f, 0.f, 0.f};

  stageA(lds.A[0], 0);
  stageB(lds.B[0], 0);
  __syncthreads();

  int cur = 0;
  for (int kk = 0; kk < DIMC; kk += 32) {
    if (kk + 32 < DIMC) {
      stageA(lds.A[cur ^ 1], kk + 32);
      stageB(lds.B[cur ^ 1], kk + 32);
    }
    const char* ap = (const char*)lds.A[cur];
    const char* bp = (const char*)lds.B[cur];
    bf16x8 af[2], bw[4];
#pragma unroll
    for (int i = 0; i < 2; ++i) {
      int row = rw + i * 16 + r;
      af[i] = *reinterpret_cast<const bf16x8*>(ap + row * 64 + ((g ^ (row & 3)) * 16));
    }
#pragma unroll
    for (int j = 0; j < 4; ++j) {
      int row = cw + j * 16 + r;
      f32x4 lo = *reinterpret_cast<const f32x4*>(
          bp + row * 128 + (((2 * g) ^ (row & 7)) << 4));
      f32x4 hi = *reinterpret_cast<const f32x4*>(
          bp + row * 128 + (((2 * g + 1) ^ (row & 7)) << 4));
      bw[j] = pack8(cvtpk(lo[0], lo[1]), cvtpk(lo[2], lo[3]),
                    cvtpk(hi[0], hi[1]), cvtpk(hi[2], hi[3]));
    }
    __builtin_amdgcn_s_setprio(1);
#pragma unroll
    for (int i = 0; i < 2; ++i)
#pragma unroll
      for (int j = 0; j < 4; ++j)
        acc[i][j] = __builtin_amdgcn_mfma_f32_16x16x32_bf16(af[i], bw[j],
                                                            acc[i][j], 0, 0, 0);
    __builtin_amdgcn_s_setprio(0);
    __syncthreads();
    cur ^= 1;
  }

#pragma unroll
  for (int i = 0; i < 2; ++i)
#pragma unroll
    for (int j = 0; j < 4; ++j) {
      int n = colB + cw + j * 16 + r;
      float bn = bias[n];
#pragma unroll
      for (int q = 0; q < 4; ++q) {
        int m = rowB + rw + i * 16 + g * 4 + q;
        float val = acc[i][j][q] + bn;
        outf[(size_t)m * DIMC + n] =
            b2f(Obf[(size_t)m * DIMC + n]) + fmaxf(val, 0.f);
      }
    }
}

// ---------------- fused masked attention, in-block split-K ----------------
// grid (32 bh, 16 qt), 512 threads = 8 waves. Wave = (kg, wq): kg picks
// even/odd 64-key tiles, wq the 32-q sub-block; each q-row covered by a PAIR
// of waves splitting the key axis -> 4096 waves = 4/SIMD with 32q/wave LDS
// economics. Fixed-max softmax => pair partials combine by pure ADDITION
// through reused LDS. Mask folded into QK MFMA C-init; K rows sigma-PERMUTED
// so swapped-QK^T D-layout per lane IS the PV A-frag order. Writes bf16 O.
__global__ __launch_bounds__(512, 4) void attn_kernel(
    const unsigned short* __restrict__ qb, const unsigned short* __restrict__ kb,
    const unsigned short* __restrict__ vt, const unsigned char* __restrict__ mask8,
    const int* __restrict__ flagp, unsigned short* __restrict__ Obf) {
  __shared__ unsigned short Kt[2][2][64 * 64];  // [pairbuf][tile]: 8KB each, 32KB
  __shared__ unsigned short Vt[2][2][64 * 64];  // [pairbuf][tile]: 32KB
  __shared__ float MaskAdd[NTOK];               // 8KB: 0 or -16384

  const int tid = threadIdx.x;
  const int lane = tid & 63;
  const int w = tid >> 6;                       // 0..7
  const int kg = w >> 2;                        // key-group: 0=even, 1=odd tile
  const int wq = w & 3;                         // q sub-block
  const int r = lane & 15, g = lane >> 4;
  const int bh = blockIdx.x, b = bh >> 3, h = bh & 7;
  const int q0 = blockIdx.y * 128 + wq * 32;
  const size_t rowbase = (size_t)b * NTOK;
  const int flag = *flagp;
  const unsigned* mask32 = (const unsigned*)mask8;

  for (int i = tid; i < NTOK; i += 512) {
    unsigned v = flag ? (unsigned)mask8[b * NTOK + i] : mask32[b * NTOK + i];
    MaskAdd[i] = v ? 0.f : -16384.f;
  }

  bf16x8 aq0[2], aq1[2];
#pragma unroll
  for (int ks = 0; ks < 2; ++ks) {
    aq0[ks] = *reinterpret_cast<const bf16x8*>(
        qb + (rowbase + q0 + r) * DIMC + h * 64 + ks * 32 + g * 8);
    aq1[ks] = *reinterpret_cast<const bf16x8*>(
        qb + (rowbase + q0 + 16 + r) * DIMC + h * 64 + ks * 32 + g * 8);
  }

  const unsigned short* kgb = kb + rowbase * DIMC + h * 64;  // + key*512
  const unsigned short* vgb = vt + (size_t)bh * 64 * NTOK;   // + d*2048 + key

  auto stageK = [&](int pb, int tile, int kt) {
    int off = tid * 16;                           // byte offset in 8KB tile
    int row = off >> 7;                           // tile row 0..63
    int s16 = ((off >> 4) & 7) ^ (row & 7);       // swizzled 16B slot
    int ff = row >> 4, gg = (row >> 2) & 3, j = row & 3;
    int tok = 8 * gg + 4 * (ff & 1) + 32 * (ff >> 1) + j;   // sigma(row)
    async_cp16(kgb + (size_t)(kt + tok) * DIMC + (s16 << 3),
               (char*)&Kt[pb][tile][0] + off);
  };
  auto stageV = [&](int pb, int tile, int kt) {
    int off = tid * 16;
    int row = off >> 7;                           // d 0..63, keys natural
    int s16 = ((off >> 4) & 7) ^ (row & 7);
    async_cp16(vgb + (size_t)row * NTOK + kt + (s16 << 3),
               (char*)&Vt[pb][tile][0] + off);
  };
  auto stagePair = [&](int pb, int p) {           // 4 cp16 / thread / pair
    stageK(pb, 0, p * 128);
    stageK(pb, 1, p * 128 + 64);
    stageV(pb, 0, p * 128);
    stageV(pb, 1, p * 128 + 64);
  };

  stagePair(0, 0);
  __syncthreads();

  float lrun0 = 0.f, lrun1 = 0.f;
  f32x4 oacc0[4], oacc1[4];
#pragma unroll
  for (int f = 0; f < 4; ++f) {
    oacc0[f] = f32x4{0.f, 0.f, 0.f, 0.f};
    oacc1[f] = f32x4{0.f, 0.f, 0.f, 0.f};
  }

  const int swz = (r & 7) << 4;

  auto softmax_pa = [&](f32x4 (&s)[4], float& lr, bf16x8 (&pa)[2]) {
#pragma unroll
    for (int f = 0; f < 4; ++f)
#pragma unroll
      for (int j = 0; j < 4; ++j) s[f][j] = __builtin_exp2f(s[f][j]);
    float sf[4];
#pragma unroll
    for (int f = 0; f < 4; ++f)
      sf[f] = (s[f][0] + s[f][1]) + (s[f][2] + s[f][3]);
    lr += (sf[0] + sf[1]) + (sf[2] + sf[3]);
#pragma unroll
    for (int ks = 0; ks < 2; ++ks)
      pa[ks] = pack8(cvtpk(s[2 * ks][0], s[2 * ks][1]),
                     cvtpk(s[2 * ks][2], s[2 * ks][3]),
                     cvtpk(s[2 * ks + 1][0], s[2 * ks + 1][1]),
                     cvtpk(s[2 * ks + 1][2], s[2 * ks + 1][3]));
  };

  int cur = 0;
  for (int p = 0; p < NTOK / 128; ++p) {          // 16 pair-iterations
    if (p + 1 < NTOK / 128) stagePair(cur ^ 1, p + 1);

    const int kt = p * 128 + kg * 64;             // this wave's tile

    f32x4 s0[4], s1[4];
#pragma unroll
    for (int f = 0; f < 4; ++f) {
      int tb = kt + 8 * g + 4 * (f & 1) + 32 * (f >> 1);
      f32x4 mc = *reinterpret_cast<const f32x4*>(&MaskAdd[tb]);
      s0[f] = mc;
      s1[f] = mc;
    }
    const unsigned char* kp = (const unsigned char*)&Kt[cur][kg][0];
    __builtin_amdgcn_s_setprio(1);
#pragma unroll
    for (int ks = 0; ks < 2; ++ks)
#pragma unroll
      for (int f = 0; f < 4; ++f) {
        bf16x8 kf = *reinterpret_cast<const bf16x8*>(
            kp + (f * 16 + r) * 128 + ((ks * 64 + g * 16) ^ swz));
        s0[f] = __builtin_amdgcn_mfma_f32_16x16x32_bf16(kf, aq0[ks], s0[f], 0, 0, 0);
        s1[f] = __builtin_amdgcn_mfma_f32_16x16x32_bf16(kf, aq1[ks], s1[f], 0, 0, 0);
      }
    __builtin_amdgcn_s_setprio(0);

    bf16x8 pa0[2], pa1[2];
    softmax_pa(s0, lrun0, pa0);
    softmax_pa(s1, lrun1, pa1);

    const unsigned char* vp = (const unsigned char*)&Vt[cur][kg][0];
    __builtin_amdgcn_s_setprio(1);
#pragma unroll
    for (int ks = 0; ks < 2; ++ks)
#pragma unroll
      for (int f = 0; f < 4; ++f) {
        bf16x8 vf = *reinterpret_cast<const bf16x8*>(
            vp + (f * 16 + r) * 128 + ((ks * 64 + g * 16) ^ swz));
        oacc0[f] = __builtin_amdgcn_mfma_f32_16x16x32_bf16(pa0[ks], vf, oacc0[f], 0, 0, 0);
        oacc1[f] = __builtin_amdgcn_mfma_f32_16x16x32_bf16(pa1[ks], vf, oacc1[f], 0, 0, 0);
      }
    __builtin_amdgcn_s_setprio(0);

    __syncthreads();  // all waves done with pairbuf cur; prefetch landed
    cur ^= 1;
  }

  // row-sum reduce across g-groups (each lane -> its row's partial sum)
  lrun0 += __shfl_xor(lrun0, 16);
  lrun0 += __shfl_xor(lrun0, 32);
  lrun1 += __shfl_xor(lrun1, 16);
  lrun1 += __shfl_xor(lrun1, 32);

  // cross-kg combine through LDS (fixed-max => pure addition). Reuse Kt/Vt.
  f32x4* cb4 = (f32x4*)&Kt[0][0][0];              // 2048 f32x4 = 32KB
  float* cl = (float*)&Vt[0][0][0];               // 128 floats
  if (kg == 1) {
#pragma unroll
    for (int f = 0; f < 4; ++f) {
      cb4[wq * 512 + f * 64 + lane] = oacc0[f];
      cb4[wq * 512 + (4 + f) * 64 + lane] = oacc1[f];
    }
    if (g == 0) {
      cl[wq * 32 + r] = lrun0;
      cl[wq * 32 + 16 + r] = lrun1;
    }
  }
  __syncthreads();
  if (kg == 0) {
#pragma unroll
    for (int f = 0; f < 4; ++f) {
      oacc0[f] += cb4[wq * 512 + f * 64 + lane];
      oacc1[f] += cb4[wq * 512 + (4 + f) * 64 + lane];
    }
    lrun0 += cl[wq * 32 + r];
    lrun1 += cl[wq * 32 + 16 + r];

    auto epilogue = [&](float lr, f32x4 (&oa)[4], int qoff) {
#pragma unroll
      for (int j = 0; j < 4; ++j) {
        float linv = 1.0f / __shfl(lr, (lane & 48) | (g * 4 + j));
        int row = q0 + qoff + g * 4 + j;
#pragma unroll
        for (int f = 0; f < 4; ++f) {
          int col = h * 64 + f * 16 + r;
          size_t idx = (rowbase + row) * DIMC + col;
          Obf[idx] = f2b(b2f(qb[idx]) + oa[f][j] * linv);
        }
      }
    };
    epilogue(lrun0, oacc0, 0);
    epilogue(lrun1, oacc1, 16);
  }
}

extern "C" void kernel_launch(void* const* d_in, const int* in_sizes, int n_in,
                              void* d_out, int out_size, void* d_ws, size_t ws_size,
                              hipStream_t stream) {
  const float* Q  = (const float*)d_in[0];
  const float* V  = (const float*)d_in[1];
  const unsigned char* mask = (const unsigned char*)d_in[2];
  const float* Wq = (const float*)d_in[3];
  const float* bq = (const float*)d_in[4];
  const float* Wk = (const float*)d_in[5];
  const float* bk = (const float*)d_in[6];
  const float* Wv = (const float*)d_in[7];
  const float* bv = (const float*)d_in[8];
  const float* Wo = (const float*)d_in[9];
  const float* bo = (const float*)d_in[10];

  char* ws = (char*)d_ws;
  size_t off = 0;
  auto alloc = [&](size_t bytes) -> void* {
    void* p = ws + off;
    off += (bytes + 255) & ~(size_t)255;
    return p;
  };
  int* flag = (int*)alloc(4);
  unsigned short* qbf = (unsigned short*)alloc((size_t)MTOK * DIMC * 2);
  unsigned short* kbf = (unsigned short*)alloc((size_t)MTOK * DIMC * 2);
  unsigned short* vtb = (unsigned short*)alloc((size_t)MTOK * DIMC * 2);
  unsigned short* Obf = (unsigned short*)alloc((size_t)MTOK * DIMC * 2);

  hipMemsetAsync(flag, 0, 4, stream);

  proj_gemm<<<dim3(64, 4, 3), 256, 0, stream>>>(
      Q, V, Wq, Wk, Wv, bq, bk, bv, qbf, kbf, vtb, mask, flag);

  attn_kernel<<<dim3(BB * 8, NTOK / 128), 512, 0, stream>>>(
      qbf, kbf, vtb, mask, flag, Obf);

  out_gemm<<<dim3(128, 4), 256, 0, stream>>>(
      Obf, Wo, bo, (float*)d_out);
}